// Round 6
// baseline (148.047 us; speedup 1.0000x reference)
//
#include <hip/hip_runtime.h>

#define BDIM 256
#define TILE_W 64
#define TILE_H 32
#define HALO 7
#define IN_R 46            // TILE_H + 14 input rows
#define CSTR 80            // cm row stride (u16): 80 slots (logical cols -1..78), 160 B
#define VSTR 82            // vm row stride (u16): 164 B = 41 dwords, gcd(41,32)=1
#define IMG 512
#define HW (IMG * IMG)
#define NPIX (16.0f * 512.0f * 512.0f)
#define P1_TASKS (IN_R * 20)   // 46 rows x 20 float4-groups = 920
#define NBLK 2048

typedef float f4 __attribute__((ext_vector_type(4)));

__device__ __forceinline__ int reflect_idx(int i, int n) {
    i = (i < 0) ? -i : i;
    i = (i >= n) ? (2 * n - 2 - i) : i;
    return i;
}

__device__ __forceinline__ unsigned short umin16(unsigned short a, unsigned short b) {
    return a < b ? a : b;
}

// clip((v+1)/2, 0, 0.1) then f32->bf16 RNE. Non-negative => u16 order == numeric.
__device__ __forceinline__ unsigned short map_bf16(float v) {
    float m = fminf(fmaxf(fmaf(v, 0.5f, 0.5f), 0.0f), 0.1f);
    unsigned int u = __float_as_uint(m);
    return (unsigned short)((u + 0x7fffu + ((u >> 16) & 1u)) >> 16);
}

__device__ __forceinline__ float bf16_f32(unsigned short x) {
    return __uint_as_float(((unsigned int)x) << 16);
}

// ---- Phase 2: vertical 15-min (u16), cm[46][CSTR] -> vm[32][VSTR]
__device__ __forceinline__ void phase2(const unsigned short* __restrict__ cm,
                                       unsigned short* __restrict__ vm, int tid) {
    if (tid < 78 * 2) {
        int col = (unsigned)tid % 78u;
        int rr0 = ((unsigned)tid / 78u) * 16;
        const unsigned short* cp = cm + (col + 1);
        unsigned short s[15];
        #pragma unroll
        for (int j = 0; j < 15; ++j) s[j] = cp[(rr0 + j) * CSTR];
        #pragma unroll
        for (int j = 13; j >= 0; --j) s[j] = umin16(s[j], s[j + 1]);
        unsigned short* vp = vm + col;
        vp[rr0 * VSTR] = s[0];
        unsigned short f = cp[(rr0 + 15) * CSTR];
        #pragma unroll
        for (int i2 = 1; i2 <= 14; ++i2) {
            vp[(rr0 + i2) * VSTR] = umin16(s[i2], f);
            f = umin16(f, cp[(rr0 + 15 + i2) * CSTR]);
        }
        vp[(rr0 + 15) * VSTR] = f;
    }
}

// ---- Phase 3: horizontal 15-min from vm -> 16 f32 regs (tid < 128 active)
__device__ __forceinline__ void phase3(const unsigned short* __restrict__ vm,
                                       int tid, float (&o)[16]) {
    int row = tid >> 2, k = tid & 3;
    const unsigned int* vr = (const unsigned int*)(vm + row * VSTR) + 8 * k;
    unsigned short x[32];
    #pragma unroll
    for (int j = 0; j < 16; ++j) {
        unsigned int d = vr[j];
        x[2 * j] = (unsigned short)d;
        x[2 * j + 1] = (unsigned short)(d >> 16);
    }
    unsigned short s[15];
    #pragma unroll
    for (int j = 0; j < 15; ++j) s[j] = x[j];
    #pragma unroll
    for (int j = 13; j >= 0; --j) s[j] = umin16(s[j], s[j + 1]);
    o[0] = bf16_f32(s[0]);
    unsigned short f = x[15];
    #pragma unroll
    for (int i2 = 1; i2 <= 14; ++i2) {
        o[i2] = bf16_f32(umin16(s[i2], f));
        f = umin16(f, x[15 + i2]);
    }
    o[15] = bf16_f32(f);
}

__global__ __launch_bounds__(BDIM, 8)
void dcl_kernel(const float* __restrict__ real, const float* __restrict__ fake,
                float* __restrict__ ws) {
    __shared__ __align__(8) unsigned short cmr[IN_R * CSTR];  // 7.36 KB
    __shared__ __align__(8) unsigned short cmf[IN_R * CSTR];  // 7.36 KB
    __shared__ __align__(8) unsigned short vm[TILE_H * VSTR]; // 5.25 KB (r then f)
    __shared__ float red[BDIM / 64];
    // total 19.98 KB -> 8 blocks/CU (159.9 KB), 32 waves/CU = max occupancy

    const int tid = threadIdx.x;
    // XCD swizzle (bid%8 -> XCD): each XCD owns a 2x8-tile panel per image so
    // halo-sharing neighbors co-reside in one L2.
    const int bid = blockIdx.x;
    const int xcd = bid & 7;
    const int r_ = bid >> 3;            // 0..255
    const int z  = r_ >> 4;             // image 0..15
    const int p  = r_ & 15;             // tile-in-panel
    const int bx = (xcd & 3) * 2 + (p & 1);    // 0..7
    const int by = (xcd >> 2) * 8 + (p >> 1);  // 0..15

    const int r0g = by * TILE_H - HALO;
    const int c0g = bx * TILE_W - HALO;
    const bool fastcol = (bx >= 1) && (bx <= 6);  // c0g-1 = 64bx-8: >=0, %4==0, +80<=512
    const size_t ib = (size_t)z * 3 * HW;
    const float* __restrict__ Rb = real + ib;
    const float* __restrict__ Fb = fake + ib;

    // ---- Phase 1: both images' loads interleaved, rely on 32-wave TLP for MLP
    #pragma unroll
    for (int i = 0; i < 4; ++i) {
        int t = tid + i * BDIM;
        t = t < (P1_TASKS - 1) ? t : (P1_TASKS - 1);   // tail clamp (benign dup)
        int row = (unsigned)t / 20u;
        int g = t - row * 20;
        int gr = reflect_idx(r0g + row, IMG);
        const float* rpR = Rb + (size_t)gr * IMG;
        const float* rpF = Fb + (size_t)gr * IMG;
        f4 R3[3], F3[3];
        if (fastcol) {
            const float* pR = rpR + (c0g - 1 + 4 * g);   // 16B-aligned
            const float* pF = rpF + (c0g - 1 + 4 * g);
            R3[0] = *(const f4*)pR;
            R3[1] = *(const f4*)(pR + HW);
            R3[2] = *(const f4*)(pR + 2 * HW);
            F3[0] = *(const f4*)pF;
            F3[1] = *(const f4*)(pF + HW);
            F3[2] = *(const f4*)(pF + 2 * HW);
        } else {
            #pragma unroll
            for (int k = 0; k < 4; ++k) {
                int gc = reflect_idx(c0g - 1 + 4 * g + k, IMG);
                R3[0][k] = rpR[gc]; R3[1][k] = rpR[HW + gc]; R3[2][k] = rpR[2 * HW + gc];
                F3[0][k] = rpF[gc]; F3[1][k] = rpF[HW + gc]; F3[2][k] = rpF[2 * HW + gc];
            }
        }
        unsigned short wr[4], wf[4];
        #pragma unroll
        for (int k = 0; k < 4; ++k) {
            wr[k] = map_bf16(fminf(R3[0][k], fminf(R3[1][k], R3[2][k])));
            wf[k] = map_bf16(fminf(F3[0][k], fminf(F3[1][k], F3[2][k])));
        }
        uint2 pr, pf;
        pr.x = (unsigned)wr[0] | ((unsigned)wr[1] << 16);
        pr.y = (unsigned)wr[2] | ((unsigned)wr[3] << 16);
        pf.x = (unsigned)wf[0] | ((unsigned)wf[1] << 16);
        pf.y = (unsigned)wf[2] | ((unsigned)wf[3] << 16);
        *(uint2*)&cmr[row * CSTR + 4 * g] = pr;
        *(uint2*)&cmf[row * CSTR + 4 * g] = pf;
    }
    __syncthreads();

    float o_r[16], o_f[16];
    phase2(cmr, vm, tid);
    __syncthreads();
    if (tid < 128) phase3(vm, tid, o_r);
    __syncthreads();                 // WAR: vm reads done before fake overwrites
    phase2(cmf, vm, tid);
    __syncthreads();
    if (tid < 128) phase3(vm, tid, o_f);

    float acc = 0.f;
    if (tid < 128) {
        #pragma unroll
        for (int i = 0; i < 16; ++i) {
            float d = o_r[i] - o_f[i];
            acc += d * d;
        }
    }
    #pragma unroll
    for (int off = 32; off >= 1; off >>= 1)
        acc += __shfl_xor(acc, off, 64);
    if ((tid & 63) == 0) red[tid >> 6] = acc;
    __syncthreads();
    if (tid == 0)
        ws[bid] = red[0] + red[1] + red[2] + red[3];
}

__global__ __launch_bounds__(256)
void reduce_kernel(const float* __restrict__ ws, float* __restrict__ out) {
    __shared__ float red[4];
    int tid = threadIdx.x;
    float a = 0.f;
    #pragma unroll
    for (int j = 0; j < 8; ++j) a += ws[tid + 256 * j];
    #pragma unroll
    for (int off = 32; off >= 1; off >>= 1)
        a += __shfl_xor(a, off, 64);
    if ((tid & 63) == 0) red[tid >> 6] = a;
    __syncthreads();
    if (tid == 0)
        out[0] = (red[0] + red[1] + red[2] + red[3]) * (1.0f / NPIX);
}

extern "C" void kernel_launch(void* const* d_in, const int* in_sizes, int n_in,
                              void* d_out, int out_size, void* d_ws, size_t ws_size,
                              hipStream_t stream) {
    const float* real = (const float*)d_in[0];
    const float* fake = (const float*)d_in[1];
    float* ws = (float*)d_ws;
    float* out = (float*)d_out;
    dcl_kernel<<<dim3(NBLK), BDIM, 0, stream>>>(real, fake, ws);
    reduce_kernel<<<1, 256, 0, stream>>>(ws, out);
}

// Round 7
// 126.312 us; speedup vs baseline: 1.1721x; 1.1721x over previous
//
#include <hip/hip_runtime.h>

#define IMG 512
#define HW (IMG * IMG)
#define NPIX (16.0f * 512.0f * 512.0f)

// ---- kernel A (streaming map) ----
#define ABLK 2048
// ---- kernel B (tiled erosion) ----
#define BDIM 256
#define TILE 64
#define HALO 7
#define IN_T 78
#define CSTR 88            // u16 units: 176 B rows (16B-aligned for uint4 writes)
#define VSTR 82            // u16 units: 164 B = 41 dwords, gcd(41,32)=1
#define NBLK_B 1024
// ---- fallback (R4 fused, verified) ----
#define FCSTR 84
#define F_P1T (IN_T * 20)

typedef float f4 __attribute__((ext_vector_type(4)));

__device__ __forceinline__ int reflect_idx(int i, int n) {
    i = (i < 0) ? -i : i;
    i = (i >= n) ? (2 * n - 2 - i) : i;
    return i;
}
__device__ __forceinline__ unsigned short umin16(unsigned short a, unsigned short b) {
    return a < b ? a : b;
}
// clip((v+1)/2,0,0.1) then f32->bf16 RNE. Non-negative => u16 order == numeric.
__device__ __forceinline__ unsigned short map_bf16(float v) {
    float m = fminf(fmaxf(fmaf(v, 0.5f, 0.5f), 0.0f), 0.1f);
    unsigned int u = __float_as_uint(m);
    return (unsigned short)((u + 0x7fffu + ((u >> 16) & 1u)) >> 16);
}
__device__ __forceinline__ float bf16_f32(unsigned short x) {
    return __uint_as_float(((unsigned int)x) << 16);
}

// ================= Kernel A: streaming channel-min map =================
// Pure copy-shaped: sequential f4 reads of all 6 planes, sequential uint2
// writes of bf16 channel-min map. No LDS, no barriers.
__global__ __launch_bounds__(256)
void map_kernel(const float* __restrict__ real, const float* __restrict__ fake,
                unsigned short* __restrict__ cmr, unsigned short* __restrict__ cmf) {
    int i0 = blockIdx.x * 256 + threadIdx.x;       // 0..524287
    #pragma unroll
    for (int u = 0; u < 2; ++u) {
        int i = i0 + u * 524288;                   // 0..1048575 = 16 * 65536 quads
        int z = i >> 16;                           // image
        int p = (i & 65535) << 2;                  // pixel offset (quad-aligned)
        const float* pr = real + (size_t)z * 3 * HW + p;
        const float* pf = fake + (size_t)z * 3 * HW + p;
        f4 r0 = *(const f4*)pr;
        f4 r1 = *(const f4*)(pr + HW);
        f4 r2 = *(const f4*)(pr + 2 * HW);
        f4 f0 = *(const f4*)pf;
        f4 f1 = *(const f4*)(pf + HW);
        f4 f2 = *(const f4*)(pf + 2 * HW);
        unsigned short wr[4], wf[4];
        #pragma unroll
        for (int k = 0; k < 4; ++k) {
            wr[k] = map_bf16(fminf(r0[k], fminf(r1[k], r2[k])));
            wf[k] = map_bf16(fminf(f0[k], fminf(f1[k], f2[k])));
        }
        uint2 ur, uf;
        ur.x = (unsigned)wr[0] | ((unsigned)wr[1] << 16);
        ur.y = (unsigned)wr[2] | ((unsigned)wr[3] << 16);
        uf.x = (unsigned)wf[0] | ((unsigned)wf[1] << 16);
        uf.y = (unsigned)wf[2] | ((unsigned)wf[3] << 16);
        *(uint2*)(cmr + (size_t)z * HW + p) = ur;
        *(uint2*)(cmf + (size_t)z * HW + p) = uf;
    }
}

// ---- shared phases (verified in R2-R5) ----
__device__ __forceinline__ void phase2(const unsigned short* __restrict__ cm,
                                       unsigned short* __restrict__ vm, int tid) {
    #pragma unroll
    for (int b = 0; b < 2; ++b) {
        int t = tid + b * BDIM;
        if (t < IN_T * 4) {
            int col = (unsigned)t % (unsigned)IN_T;
            int rr0 = ((unsigned)t / (unsigned)IN_T) * 16;
            const unsigned short* cp = cm + (col + 1);
            unsigned short s[15];
            #pragma unroll
            for (int j = 0; j < 15; ++j) s[j] = cp[(rr0 + j) * CSTR];
            #pragma unroll
            for (int j = 13; j >= 0; --j) s[j] = umin16(s[j], s[j + 1]);
            unsigned short* vp = vm + col;
            vp[rr0 * VSTR] = s[0];
            unsigned short f = cp[(rr0 + 15) * CSTR];
            #pragma unroll
            for (int i2 = 1; i2 <= 14; ++i2) {
                vp[(rr0 + i2) * VSTR] = umin16(s[i2], f);
                f = umin16(f, cp[(rr0 + 15 + i2) * CSTR]);
            }
            vp[(rr0 + 15) * VSTR] = f;
        }
    }
}

__device__ __forceinline__ void phase3(const unsigned short* __restrict__ vm,
                                       int tid, float (&o)[16]) {
    int row = tid >> 2, k = tid & 3;
    const unsigned int* vr = (const unsigned int*)(vm + row * VSTR) + 8 * k;
    unsigned short x[32];
    #pragma unroll
    for (int j = 0; j < 16; ++j) {
        unsigned int d = vr[j];
        x[2 * j] = (unsigned short)d;
        x[2 * j + 1] = (unsigned short)(d >> 16);
    }
    unsigned short s[15];
    #pragma unroll
    for (int j = 0; j < 15; ++j) s[j] = x[j];
    #pragma unroll
    for (int j = 13; j >= 0; --j) s[j] = umin16(s[j], s[j + 1]);
    o[0] = bf16_f32(s[0]);
    unsigned short f = x[15];
    #pragma unroll
    for (int i2 = 1; i2 <= 14; ++i2) {
        o[i2] = bf16_f32(umin16(s[i2], f));
        f = umin16(f, x[15 + i2]);
    }
    o[15] = bf16_f32(f);
}

// ================= Kernel B: tiled erosion + MSE from bf16 map =================
__global__ __launch_bounds__(BDIM)
void dcl_tile(const unsigned short* __restrict__ cmr_g,
              const unsigned short* __restrict__ cmf_g,
              float* __restrict__ ws) {
    __shared__ __align__(16) unsigned short cmr[IN_T * CSTR];  // 13.7 KB
    __shared__ __align__(16) unsigned short cmf[IN_T * CSTR];  // 13.7 KB
    __shared__ __align__(8) unsigned short vm[TILE * VSTR];    // 10.5 KB
    __shared__ float red[BDIM / 64];

    const int tid = threadIdx.x;
    // XCD panel swizzle (R4, verified): each XCD owns a 4x2-tile panel / image.
    const int bid = blockIdx.x;
    const int xcd = bid & 7;
    const int s_ = bid >> 3;
    const int z = s_ & 15;
    const int tt = s_ >> 4;
    const int bx = (xcd & 1) * 4 + (tt & 3);
    const int by = (xcd >> 1) * 2 + (tt >> 2);

    const int r0g = by * TILE - HALO;
    const int c0g = bx * TILE - HALO;
    const bool fastcol = (bx >= 1) && (bx <= 6);   // slot0 col = 64bx-8 >=0, slot79 <= 511
    const unsigned short* br = cmr_g + (size_t)z * HW;
    const unsigned short* bf = cmf_g + (size_t)z * HW;

    // Phase 1: load bf16 tiles (78 rows x 80 slots; slot s <-> col c0g-1+s)
    #pragma unroll
    for (int it = 0; it < 4; ++it) {
        int t = tid + it * BDIM;
        t = t < 779 ? t : 779;                     // 78*10 tasks, clamp (benign dup)
        int row = (unsigned)t / 10u;
        int g = t - row * 10;
        int gr = reflect_idx(r0g + row, IMG);
        const unsigned short* rr = br + (size_t)gr * IMG;
        const unsigned short* rf = bf + (size_t)gr * IMG;
        if (fastcol) {
            int gc = c0g - 1 + 8 * g;              // 16B-aligned (64bx-8+8g)
            uint4 qr = *(const uint4*)(rr + gc);
            uint4 qf = *(const uint4*)(rf + gc);
            *(uint4*)&cmr[row * CSTR + 8 * g] = qr;
            *(uint4*)&cmf[row * CSTR + 8 * g] = qf;
        } else {
            #pragma unroll
            for (int k = 0; k < 8; ++k) {
                int gc = reflect_idx(c0g - 1 + 8 * g + k, IMG);
                cmr[row * CSTR + 8 * g + k] = rr[gc];
                cmf[row * CSTR + 8 * g + k] = rf[gc];
            }
        }
    }
    __syncthreads();

    float o_r[16], o_f[16];
    phase2(cmr, vm, tid);
    __syncthreads();
    phase3(vm, tid, o_r);
    __syncthreads();
    phase2(cmf, vm, tid);
    __syncthreads();
    phase3(vm, tid, o_f);

    float acc = 0.f;
    #pragma unroll
    for (int i = 0; i < 16; ++i) {
        float d = o_r[i] - o_f[i];
        acc += d * d;
    }
    #pragma unroll
    for (int off = 32; off >= 1; off >>= 1)
        acc += __shfl_xor(acc, off, 64);
    if ((tid & 63) == 0) red[tid >> 6] = acc;
    __syncthreads();
    if (tid == 0)
        ws[bid] = red[0] + red[1] + red[2] + red[3];
}

// ================= Fallback: R4 fused kernel (verified), used if ws too small ====
__global__ __launch_bounds__(BDIM, 4)
void dcl_fused(const float* __restrict__ real, const float* __restrict__ fake,
               float* __restrict__ ws) {
    __shared__ __align__(8) unsigned short cmr[IN_T * FCSTR];
    __shared__ __align__(8) unsigned short cmf[IN_T * FCSTR];
    __shared__ __align__(8) unsigned short vmf[TILE * VSTR];
    __shared__ float red[BDIM / 64];

    const int tid = threadIdx.x;
    const int bid = blockIdx.x;
    const int xcd = bid & 7;
    const int s_ = bid >> 3;
    const int z = s_ & 15;
    const int tt = s_ >> 4;
    const int bx = (xcd & 1) * 4 + (tt & 3);
    const int by = (xcd >> 1) * 2 + (tt >> 2);

    const int r0g = by * TILE - HALO;
    const int c0g = bx * TILE - HALO;
    const bool fastcol = (bx >= 1) && (bx <= 6);
    const size_t ib = (size_t)z * 3 * HW;
    const float* __restrict__ Rb = real + ib;
    const float* __restrict__ Fb = fake + ib;

    #pragma unroll
    for (int i = 0; i < 7; ++i) {
        int t = tid + i * BDIM;
        t = t < (F_P1T - 1) ? t : (F_P1T - 1);
        int row = (unsigned)t / 20u;
        int g = t - row * 20;
        int gr = reflect_idx(r0g + row, IMG);
        const float* rpR = Rb + (size_t)gr * IMG;
        const float* rpF = Fb + (size_t)gr * IMG;
        f4 R3[3], F3[3];
        if (fastcol) {
            const float* pR = rpR + (c0g - 1 + 4 * g);
            const float* pF = rpF + (c0g - 1 + 4 * g);
            R3[0] = *(const f4*)pR; R3[1] = *(const f4*)(pR + HW); R3[2] = *(const f4*)(pR + 2 * HW);
            F3[0] = *(const f4*)pF; F3[1] = *(const f4*)(pF + HW); F3[2] = *(const f4*)(pF + 2 * HW);
        } else {
            #pragma unroll
            for (int k = 0; k < 4; ++k) {
                int gc = reflect_idx(c0g - 1 + 4 * g + k, IMG);
                R3[0][k] = rpR[gc]; R3[1][k] = rpR[HW + gc]; R3[2][k] = rpR[2 * HW + gc];
                F3[0][k] = rpF[gc]; F3[1][k] = rpF[HW + gc]; F3[2][k] = rpF[2 * HW + gc];
            }
        }
        unsigned short wr[4], wf[4];
        #pragma unroll
        for (int k = 0; k < 4; ++k) {
            wr[k] = map_bf16(fminf(R3[0][k], fminf(R3[1][k], R3[2][k])));
            wf[k] = map_bf16(fminf(F3[0][k], fminf(F3[1][k], F3[2][k])));
        }
        uint2 pr, pf;
        pr.x = (unsigned)wr[0] | ((unsigned)wr[1] << 16);
        pr.y = (unsigned)wr[2] | ((unsigned)wr[3] << 16);
        pf.x = (unsigned)wf[0] | ((unsigned)wf[1] << 16);
        pf.y = (unsigned)wf[2] | ((unsigned)wf[3] << 16);
        *(uint2*)&cmr[row * FCSTR + 4 * g] = pr;
        *(uint2*)&cmf[row * FCSTR + 4 * g] = pf;
    }
    __syncthreads();

    float o_r[16], o_f[16];
    // phase2 with FCSTR stride (inline copies)
    #pragma unroll
    for (int b = 0; b < 2; ++b) {
        int t = tid + b * BDIM;
        if (t < IN_T * 4) {
            int col = (unsigned)t % (unsigned)IN_T;
            int rr0 = ((unsigned)t / (unsigned)IN_T) * 16;
            const unsigned short* cp = cmr + (col + 1);
            unsigned short s[15];
            #pragma unroll
            for (int j = 0; j < 15; ++j) s[j] = cp[(rr0 + j) * FCSTR];
            #pragma unroll
            for (int j = 13; j >= 0; --j) s[j] = umin16(s[j], s[j + 1]);
            unsigned short* vp = vmf + col;
            vp[rr0 * VSTR] = s[0];
            unsigned short f = cp[(rr0 + 15) * FCSTR];
            #pragma unroll
            for (int i2 = 1; i2 <= 14; ++i2) {
                vp[(rr0 + i2) * VSTR] = umin16(s[i2], f);
                f = umin16(f, cp[(rr0 + 15 + i2) * FCSTR]);
            }
            vp[(rr0 + 15) * VSTR] = f;
        }
    }
    __syncthreads();
    phase3(vmf, tid, o_r);
    __syncthreads();
    #pragma unroll
    for (int b = 0; b < 2; ++b) {
        int t = tid + b * BDIM;
        if (t < IN_T * 4) {
            int col = (unsigned)t % (unsigned)IN_T;
            int rr0 = ((unsigned)t / (unsigned)IN_T) * 16;
            const unsigned short* cp = cmf + (col + 1);
            unsigned short s[15];
            #pragma unroll
            for (int j = 0; j < 15; ++j) s[j] = cp[(rr0 + j) * FCSTR];
            #pragma unroll
            for (int j = 13; j >= 0; --j) s[j] = umin16(s[j], s[j + 1]);
            unsigned short* vp = vmf + col;
            vp[rr0 * VSTR] = s[0];
            unsigned short f = cp[(rr0 + 15) * FCSTR];
            #pragma unroll
            for (int i2 = 1; i2 <= 14; ++i2) {
                vp[(rr0 + i2) * VSTR] = umin16(s[i2], f);
                f = umin16(f, cp[(rr0 + 15 + i2) * FCSTR]);
            }
            vp[(rr0 + 15) * VSTR] = f;
        }
    }
    __syncthreads();
    phase3(vmf, tid, o_f);

    float acc = 0.f;
    #pragma unroll
    for (int i = 0; i < 16; ++i) {
        float d = o_r[i] - o_f[i];
        acc += d * d;
    }
    #pragma unroll
    for (int off = 32; off >= 1; off >>= 1)
        acc += __shfl_xor(acc, off, 64);
    if ((tid & 63) == 0) red[tid >> 6] = acc;
    __syncthreads();
    if (tid == 0)
        ws[bid] = red[0] + red[1] + red[2] + red[3];
}

__global__ __launch_bounds__(256)
void reduce_kernel(const float* __restrict__ ws, float* __restrict__ out) {
    __shared__ float red[4];
    int tid = threadIdx.x;
    float a = ws[tid] + ws[tid + 256] + ws[tid + 512] + ws[tid + 768];
    #pragma unroll
    for (int off = 32; off >= 1; off >>= 1)
        a += __shfl_xor(a, off, 64);
    if ((tid & 63) == 0) red[tid >> 6] = a;
    __syncthreads();
    if (tid == 0)
        out[0] = (red[0] + red[1] + red[2] + red[3]) * (1.0f / NPIX);
}

extern "C" void kernel_launch(void* const* d_in, const int* in_sizes, int n_in,
                              void* d_out, int out_size, void* d_ws, size_t ws_size,
                              hipStream_t stream) {
    const float* real = (const float*)d_in[0];
    const float* fake = (const float*)d_in[1];
    float* ws = (float*)d_ws;
    float* out = (float*)d_out;

    const size_t cm_bytes = (size_t)16 * HW * 2;           // 8.39 MB per tensor
    const size_t need = 8192 + 2 * cm_bytes;               // ~16.8 MB
    if (ws_size >= need) {
        unsigned short* cmr = (unsigned short*)((char*)d_ws + 8192);
        unsigned short* cmf = (unsigned short*)((char*)d_ws + 8192 + cm_bytes);
        map_kernel<<<dim3(ABLK), 256, 0, stream>>>(real, fake, cmr, cmf);
        dcl_tile<<<dim3(NBLK_B), BDIM, 0, stream>>>(cmr, cmf, ws);
    } else {
        dcl_fused<<<dim3(NBLK_B), BDIM, 0, stream>>>(real, fake, ws);
    }
    reduce_kernel<<<1, 256, 0, stream>>>(ws, out);
}